// Round 17
// baseline (481.545 us; speedup 1.0000x reference)
//
#include <hip/hip_runtime.h>
#include <hip/hip_bf16.h>
#include <hip/hip_fp16.h>
#include <math.h>

#define NN 50000
#define EE 400000
#define ETOT (NN + EE)

// ---------- helpers ----------
__device__ __forceinline__ float gelu_f(float x) {
    return 0.5f * x * (1.f + erff(x * 0.7071067811865476f));
}
__device__ __forceinline__ float elu_f(float x) {
    return x > 0.f ? x : expm1f(x);
}
__device__ __forceinline__ float4 half8_lo_hi(uint4 raw, float4* hi) {
    __half2 h0 = *(__half2*)&raw.x, h1 = *(__half2*)&raw.y;
    __half2 h2 = *(__half2*)&raw.z, h3 = *(__half2*)&raw.w;
    float2 f0 = __half22float2(h0), f1 = __half22float2(h1);
    float2 f2 = __half22float2(h2), f3 = __half22float2(h3);
    *hi = make_float4(f2.x, f2.y, f3.x, f3.y);
    return make_float4(f0.x, f0.y, f1.x, f1.y);
}
__device__ __forceinline__ float4 half4_to_f4(uint2 raw) {
    __half2 a = *(__half2*)&raw.x, b = *(__half2*)&raw.y;
    float2 fa = __half22float2(a), fb = __half22float2(b);
    return make_float4(fa.x, fa.y, fb.x, fb.y);
}
__device__ __forceinline__ uint2 f4_to_half4(float4 v) {
    __half2 h0 = __floats2half2_rn(v.x, v.y);
    __half2 h1 = __floats2half2_rn(v.z, v.w);
    uint2 pk;
    pk.x = *(unsigned*)&h0;
    pk.y = *(unsigned*)&h1;
    return pk;
}
__device__ __forceinline__ uint4 pack8_half(float4 a, float4 b) {
    __half2 q0 = __floats2half2_rn(a.x, a.y), q1 = __floats2half2_rn(a.z, a.w);
    __half2 q2 = __floats2half2_rn(b.x, b.y), q3 = __floats2half2_rn(b.z, b.w);
    uint4 pk;
    pk.x = *(unsigned*)&q0; pk.y = *(unsigned*)&q1;
    pk.z = *(unsigned*)&q2; pk.w = *(unsigned*)&q3;
    return pk;
}
__device__ __forceinline__ void unpack8_half(int x, int y, int z, int w, float* ev) {
    float2 f0 = __half22float2(*(__half2*)&x);
    float2 f1 = __half22float2(*(__half2*)&y);
    float2 f2 = __half22float2(*(__half2*)&z);
    float2 f3 = __half22float2(*(__half2*)&w);
    ev[0] = f0.x; ev[1] = f0.y; ev[2] = f1.x; ev[3] = f1.y;
    ev[4] = f2.x; ev[5] = f2.y; ev[6] = f3.x; ev[7] = f3.y;
}

// ---------- combined: ea mean (sum) + ea->fp16 copy [blocks 0..255] + degree count [blocks 256..] ----------
__global__ __launch_bounds__(256) void k_init(const float* __restrict__ ea, float* __restrict__ ea_sum,
                                              __half* __restrict__ eah,
                                              const int* __restrict__ ei, int* __restrict__ counts,
                                              int E, int N) {
    int t = threadIdx.x;
    if (blockIdx.x < 256) {
        float s[8];
#pragma unroll
        for (int i = 0; i < 8; i++) s[i] = 0.f;
        for (int e = blockIdx.x * 256 + t; e < E; e += 256 * 256) {
            const float4* p = (const float4*)(ea + (size_t)e * 8);
            float4 a = p[0], b = p[1];
            s[0] += a.x; s[1] += a.y; s[2] += a.z; s[3] += a.w;
            s[4] += b.x; s[5] += b.y; s[6] += b.z; s[7] += b.w;
            *(uint4*)(eah + (size_t)e * 8) = pack8_half(a, b);
        }
#pragma unroll
        for (int o = 32; o; o >>= 1)
#pragma unroll
            for (int i = 0; i < 8; i++) s[i] += __shfl_xor(s[i], o, 64);
        __shared__ float sh[4][8];
        int lane = t & 63, w = t >> 6;
        if (lane == 0)
#pragma unroll
            for (int i = 0; i < 8; i++) sh[w][i] = s[i];
        __syncthreads();
        if (t < 8) {
            float v = sh[0][t] + sh[1][t] + sh[2][t] + sh[3][t];
            atomicAdd(ea_sum + t, v);
        }
    } else {
        int e = (blockIdx.x - 256) * 256 + t;
        if (e >= E + N) return;
        int d = (e < E) ? ei[E + e] : (e - E);
        atomicAdd(counts + d, 1);
    }
}

// ---------- scan (4 elems/thread) ----------
__global__ __launch_bounds__(1024) void k_scan(const int* __restrict__ counts, int* __restrict__ off,
                                               int* __restrict__ cursor, int N) {
    __shared__ int buf[1024];
    int t = threadIdx.x;
    int carry = 0;
    if (t == 0) off[0] = 0;
    for (int base = 0; base < N; base += 4096) {
        int i0 = base + t * 4;
        int v0 = 0, v1 = 0, v2 = 0, v3 = 0;
        if (i0 + 3 < N) {
            int4 vv = *(const int4*)(counts + i0);
            v0 = vv.x; v1 = vv.y; v2 = vv.z; v3 = vv.w;
        } else {
            if (i0 < N)     v0 = counts[i0];
            if (i0 + 1 < N) v1 = counts[i0 + 1];
            if (i0 + 2 < N) v2 = counts[i0 + 2];
            if (i0 + 3 < N) v3 = counts[i0 + 3];
        }
        int s01 = v0 + v1, s012 = s01 + v2, tot4 = s012 + v3;
        buf[t] = tot4;
        __syncthreads();
        for (int o = 1; o < 1024; o <<= 1) {
            int add = (t >= o) ? buf[t - o] : 0;
            __syncthreads();
            buf[t] += add;
            __syncthreads();
        }
        int incl4 = buf[t] + carry;
        int excl = incl4 - tot4;
        if (i0 < N)     { off[i0 + 1] = excl + v0;   cursor[i0]     = excl; }
        if (i0 + 1 < N) { off[i0 + 2] = excl + s01;  cursor[i0 + 1] = excl + v0; }
        if (i0 + 2 < N) { off[i0 + 3] = excl + s012; cursor[i0 + 2] = excl + s01; }
        if (i0 + 3 < N) { off[i0 + 4] = excl + tot4; cursor[i0 + 3] = excl + s012; }
        int tot = buf[1023];
        __syncthreads();
        carry += tot;
    }
}

// ---------- combined: scatter [blocks 0..S) + ntrans1 [blocks S..) ----------
__global__ __launch_bounds__(256) void k_scat_nt1(const int* __restrict__ ei, int* __restrict__ cursor,
                                                  int* __restrict__ csr_src, int* __restrict__ csr_eid,
                                                  const float* __restrict__ x,
                                                  const float* __restrict__ Wl, const float* __restrict__ bl,
                                                  const float* __restrict__ Wr, const float* __restrict__ br,
                                                  __half* __restrict__ xl1h, __half* __restrict__ xr1h,
                                                  int E, int N) {
    __shared__ float swl[16 * 256];
    __shared__ float swr[16 * 256];
    __shared__ float sx[32 * 16];
    int t = threadIdx.x;
    int S = (E + N + 255) >> 8;
    if ((int)blockIdx.x < S) {
        int e = blockIdx.x * 256 + t;
        if (e >= E + N) return;
        int s, d;
        if (e < E) { s = ei[e]; d = ei[E + e]; }
        else { s = d = e - E; }
        int pos = atomicAdd(cursor + d, 1);
        csr_src[pos] = s;
        csr_eid[pos] = e;
        return;
    }
    int bid = blockIdx.x - S;
#pragma unroll
    for (int k = 0; k < 16; k++) { swl[k * 256 + t] = Wl[k * 256 + t]; swr[k * 256 + t] = Wr[k * 256 + t]; }
    int n0 = bid * 32;
    for (int i = t; i < 32 * 16; i += 256) {
        int n = n0 + (i >> 4);
        sx[i] = (n < N) ? x[(size_t)n * 16 + (i & 15)] : 0.f;
    }
    __syncthreads();
    float bL = bl[t], bR = br[t];
    for (int ni = 0; ni < 32; ni++) {
        int n = n0 + ni;
        if (n >= N) break;
        float al = bL, ar = bR;
#pragma unroll
        for (int k = 0; k < 16; k++) {
            float xv = sx[ni * 16 + k];
            al += xv * swl[k * 256 + t];
            ar += xv * swr[k * 256 + t];
        }
        xl1h[(size_t)n * 256 + t] = __float2half(al);
        xr1h[(size_t)n * 256 + t] = __float2half(ar);
    }
}

// ---------- fused conv1: dual-edge ILP, packed-ea broadcast, depth-4 prefetch, no-shift softmax ----------
__global__ __launch_bounds__(256) void k_fagg1(const __half* __restrict__ xl1h, const __half* __restrict__ xr1h,
                                               const int* __restrict__ off, const int* __restrict__ csr_src,
                                               const int* __restrict__ csr_eid,
                                               const __half* __restrict__ eah, const float* __restrict__ ea_sum,
                                               const float* __restrict__ We1, const float* __restrict__ att1,
                                               const float* __restrict__ bias1,
                                               const float* __restrict__ x, const float* __restrict__ Wres,
                                               const float* __restrict__ g, const float* __restrict__ bb_,
                                               const float* __restrict__ mm_, const float* __restrict__ vv_,
                                               __half* __restrict__ h1h,
                                               int E, int N) {
    int t = threadIdx.x;
    int lane = t & 63, w = t >> 6;
    int node = blockIdx.x * 4 + w;
    if (node >= N) return;
    int c4 = lane * 4;
    float4 we[8];
#pragma unroll
    for (int k = 0; k < 8; k++) we[k] = *(const float4*)(We1 + k * 256 + c4);
    float4 xr4 = half4_to_f4(*(const uint2*)(xr1h + (size_t)node * 256 + c4));
    float4 at4 = *(const float4*)(att1 + c4);
    float invE = 1.f / (float)E;
    float4 eam0, eam1;
    eam0.x = ea_sum[0] * invE; eam0.y = ea_sum[1] * invE;
    eam0.z = ea_sum[2] * invE; eam0.w = ea_sum[3] * invE;
    eam1.x = ea_sum[4] * invE; eam1.y = ea_sum[5] * invE;
    eam1.z = ea_sum[6] * invE; eam1.w = ea_sum[7] * invE;
    uint4 eamp = pack8_half(eam0, eam1);

    int beg = off[node], end = off[node + 1];
    float sumw = 0.f;
    float4 acc = make_float4(0.f, 0.f, 0.f, 0.f);

    int cb = beg;
    while (cb < end) {
        int cnt = end - cb; if (cnt > 64) cnt = 64;
        int sl = 0;
        uint4 pea = eamp;
        if (lane < cnt) {
            sl = csr_src[cb + lane];
            int el = csr_eid[cb + lane];
            if (el < E) pea = *(const uint4*)(eah + (size_t)el * 8);
        }
        // depth-4 rotating row prefetch; consume 2/iter
        float2 r0, r1, r2, r3;
        {
            int s0 = __shfl(sl, 0, 64);
            r0 = *(const float2*)(xl1h + (size_t)s0 * 256 + c4);
            int s1 = __shfl(sl, 1 & 63, 64);
            r1 = *(const float2*)(xl1h + (size_t)s1 * 256 + c4);
            int s2 = __shfl(sl, 2 & 63, 64);
            r2 = *(const float2*)(xl1h + (size_t)s2 * 256 + c4);
            int s3 = __shfl(sl, 3 & 63, 64);
            r3 = *(const float2*)(xl1h + (size_t)s3 * 256 + c4);
        }
        for (int j = 0; j < cnt; j += 2) {
            float2 curA = r0, curB = r1;
            r0 = r2; r1 = r3;
            if (j + 4 < cnt) {
                int s4 = __shfl(sl, j + 4, 64);
                r2 = *(const float2*)(xl1h + (size_t)s4 * 256 + c4);
            }
            if (j + 5 < cnt) {
                int s5 = __shfl(sl, j + 5, 64);
                r3 = *(const float2*)(xl1h + (size_t)s5 * 256 + c4);
            }
            // packed-ea broadcast for both edges
            int exA = __shfl((int)pea.x, j, 64);
            int eyA = __shfl((int)pea.y, j, 64);
            int ezA = __shfl((int)pea.z, j, 64);
            int ewA = __shfl((int)pea.w, j, 64);
            int exB = __shfl((int)pea.x, (j + 1) & 63, 64);
            int eyB = __shfl((int)pea.y, (j + 1) & 63, 64);
            int ezB = __shfl((int)pea.z, (j + 1) & 63, 64);
            int ewB = __shfl((int)pea.w, (j + 1) & 63, 64);
            float eavA[8], eavB[8];
            unpack8_half(exA, eyA, ezA, ewA, eavA);
            unpack8_half(exB, eyB, ezB, ewB, eavB);
            const __half2* hpA = (const __half2*)&curA;
            float2 loA = __half22float2(hpA[0]);
            float2 hiA = __half22float2(hpA[1]);
            float4 xsA = make_float4(loA.x, loA.y, hiA.x, hiA.y);
            const __half2* hpB = (const __half2*)&curB;
            float2 loB = __half22float2(hpB[0]);
            float2 hiB = __half22float2(hpB[1]);
            float4 xsB = make_float4(loB.x, loB.y, hiB.x, hiB.y);
            float4 eeA = make_float4(0.f, 0.f, 0.f, 0.f);
            float4 eeB = make_float4(0.f, 0.f, 0.f, 0.f);
#pragma unroll
            for (int k = 0; k < 8; k++) {
                eeA.x += eavA[k] * we[k].x; eeA.y += eavA[k] * we[k].y;
                eeA.z += eavA[k] * we[k].z; eeA.w += eavA[k] * we[k].w;
                eeB.x += eavB[k] * we[k].x; eeB.y += eavB[k] * we[k].y;
                eeB.z += eavB[k] * we[k].z; eeB.w += eavB[k] * we[k].w;
            }
            float4 vA, vB;
            vA.x = xsA.x + xr4.x + eeA.x; vA.y = xsA.y + xr4.y + eeA.y;
            vA.z = xsA.z + xr4.z + eeA.z; vA.w = xsA.w + xr4.w + eeA.w;
            vB.x = xsB.x + xr4.x + eeB.x; vB.y = xsB.y + xr4.y + eeB.y;
            vB.z = xsB.z + xr4.z + eeB.z; vB.w = xsB.w + xr4.w + eeB.w;
            vA.x = vA.x > 0.f ? vA.x : 0.2f * vA.x;
            vA.y = vA.y > 0.f ? vA.y : 0.2f * vA.y;
            vA.z = vA.z > 0.f ? vA.z : 0.2f * vA.z;
            vA.w = vA.w > 0.f ? vA.w : 0.2f * vA.w;
            vB.x = vB.x > 0.f ? vB.x : 0.2f * vB.x;
            vB.y = vB.y > 0.f ? vB.y : 0.2f * vB.y;
            vB.z = vB.z > 0.f ? vB.z : 0.2f * vB.z;
            vB.w = vB.w > 0.f ? vB.w : 0.2f * vB.w;
            float pA = vA.x * at4.x + vA.y * at4.y + vA.z * at4.z + vA.w * at4.w;
            float pB = vB.x * at4.x + vB.y * at4.y + vB.z * at4.z + vB.w * at4.w;
            pA += __shfl_xor(pA, 1, 64);
            pB += __shfl_xor(pB, 1, 64);
            pA += __shfl_xor(pA, 2, 64);
            pB += __shfl_xor(pB, 2, 64);
            pA += __shfl_xor(pA, 4, 64);
            pB += __shfl_xor(pB, 4, 64);
            pA += __shfl_xor(pA, 8, 64);
            pB += __shfl_xor(pB, 8, 64);
            float wa = expf(pA);
            float wb = (j + 1 < cnt) ? expf(pB) : 0.f;
            acc.x += wa * xsA.x + wb * xsB.x;
            acc.y += wa * xsA.y + wb * xsB.y;
            acc.z += wa * xsA.z + wb * xsB.z;
            acc.w += wa * xsA.w + wb * xsB.w;
            sumw += wa + wb;
        }
        cb += cnt;
    }
    float inv = 1.f / (sumw + 1e-16f);
    float4 r = make_float4(0.f, 0.f, 0.f, 0.f);
#pragma unroll
    for (int q = 0; q < 4; q++) {
        float4 xq = *(const float4*)(x + (size_t)node * 16 + q * 4);
        float xa[4] = { xq.x, xq.y, xq.z, xq.w };
#pragma unroll
        for (int kk = 0; kk < 4; kk++) {
            float4 wv = *(const float4*)(Wres + (size_t)(q * 4 + kk) * 256 + c4);
            r.x += xa[kk] * wv.x; r.y += xa[kk] * wv.y;
            r.z += xa[kk] * wv.z; r.w += xa[kk] * wv.w;
        }
    }
    float4 bi = *(const float4*)(bias1 + c4);
    float4 g4 = *(const float4*)(g + c4);
    float4 b4 = *(const float4*)(bb_ + c4);
    float4 m4 = *(const float4*)(mm_ + c4);
    float4 v4 = *(const float4*)(vv_ + c4);
    float4 o;
    o.x = acc.x * inv + bi.x; o.y = acc.y * inv + bi.y;
    o.z = acc.z * inv + bi.z; o.w = acc.w * inv + bi.w;
    o.x = (o.x - m4.x) * rsqrtf(v4.x + 1e-5f) * g4.x + b4.x + r.x;
    o.y = (o.y - m4.y) * rsqrtf(v4.y + 1e-5f) * g4.y + b4.y + r.y;
    o.z = (o.z - m4.z) * rsqrtf(v4.z + 1e-5f) * g4.z + b4.z + r.z;
    o.w = (o.w - m4.w) * rsqrtf(v4.w + 1e-5f) * g4.w + b4.w + r.w;
    o.x = elu_f(o.x); o.y = elu_f(o.y); o.z = elu_f(o.z); o.w = elu_f(o.w);
    *(uint2*)(h1h + (size_t)node * 256 + c4) = f4_to_half4(o);
}

// ---------- xl2(fp16) = h1@Wl2+bl2, xr2(fp16) = h1@Wr2+br2 (h1 fp16 in) ----------
__global__ __launch_bounds__(256) void k_xlr2(const __half* __restrict__ h1h,
                                              const float* __restrict__ Wl2, const float* __restrict__ bl2,
                                              const float* __restrict__ Wr2, const float* __restrict__ br2,
                                              __half* __restrict__ xl2h, __half* __restrict__ xr2h, int N) {
    __shared__ float sh[32][32];    // [kk][node]
    __shared__ float sw[32][128];   // [kk][col]
    int t = threadIdx.x;
    int tr = t >> 5, tc = t & 31;
    int n0 = blockIdx.x * 32;
    float acc[4][4];
#pragma unroll
    for (int i = 0; i < 4; i++)
#pragma unroll
        for (int j = 0; j < 4; j++) acc[i][j] = 0.f;
    for (int k0 = 0; k0 < 256; k0 += 32) {
        {
            int n = t >> 3, kk0 = (t & 7) * 4;
            int gn = n0 + n;
            float4 hv = make_float4(0.f, 0.f, 0.f, 0.f);
            if (gn < N) hv = half4_to_f4(*(const uint2*)(h1h + (size_t)gn * 256 + k0 + kk0));
            sh[kk0 + 0][n] = hv.x; sh[kk0 + 1][n] = hv.y; sh[kk0 + 2][n] = hv.z; sh[kk0 + 3][n] = hv.w;
        }
        for (int i = t; i < 32 * 128; i += 256) {
            int kk = i >> 7, c = i & 127;
            sw[kk][c] = (c < 64) ? Wl2[(size_t)(k0 + kk) * 64 + c] : Wr2[(size_t)(k0 + kk) * 64 + (c - 64)];
        }
        __syncthreads();
#pragma unroll
        for (int kk = 0; kk < 32; kk++) {
            float4 hv = *(const float4*)&sh[kk][tr * 4];
            float4 wv = *(const float4*)&sw[kk][tc * 4];
            float hh[4] = { hv.x, hv.y, hv.z, hv.w };
            float wwv[4] = { wv.x, wv.y, wv.z, wv.w };
#pragma unroll
            for (int i = 0; i < 4; i++)
#pragma unroll
                for (int j = 0; j < 4; j++) acc[i][j] += hh[i] * wwv[j];
        }
        __syncthreads();
    }
#pragma unroll
    for (int i = 0; i < 4; i++) {
        int gn = n0 + tr * 4 + i;
        if (gn >= N) continue;
#pragma unroll
        for (int j = 0; j < 4; j++) {
            int c = tc * 4 + j;
            float vv = acc[i][j];
            if (c < 64) xl2h[(size_t)gn * 64 + c] = __float2half(vv + bl2[c]);
            else        xr2h[(size_t)gn * 64 + (c - 64)] = __float2half(vv + br2[c - 64]);
        }
    }
}

// ---------- fused conv2 v3: 4 edges/wave, packed-ea broadcast, no-shift softmax ----------
__global__ __launch_bounds__(256) void k_fagg2(const __half* __restrict__ xl2h, const __half* __restrict__ xr2h,
                                               const int* __restrict__ off, const int* __restrict__ csr_src,
                                               const int* __restrict__ csr_eid,
                                               const __half* __restrict__ eah, const float* __restrict__ ea_sum,
                                               const float* __restrict__ We2, const float* __restrict__ att2,
                                               const float* __restrict__ bias2,
                                               const float* __restrict__ g, const float* __restrict__ bb_,
                                               const float* __restrict__ mm_, const float* __restrict__ vv_,
                                               __half* __restrict__ h2h,
                                               int E, int N) {
    int t = threadIdx.x;
    int lane = t & 63, w = t >> 6;
    int node = blockIdx.x * 4 + w;
    if (node >= N) return;
    int seg = lane >> 4;          // edge slot 0..3
    int c4 = (lane & 15) * 4;     // 4 channels owned
    float4 we[8];
#pragma unroll
    for (int k = 0; k < 8; k++) we[k] = *(const float4*)(We2 + k * 64 + c4);
    float4 xr4 = half4_to_f4(*(const uint2*)(xr2h + (size_t)node * 64 + c4));
    float4 at4 = *(const float4*)(att2 + c4);
    float invE = 1.f / (float)E;
    float4 eam0, eam1;
    eam0.x = ea_sum[0] * invE; eam0.y = ea_sum[1] * invE;
    eam0.z = ea_sum[2] * invE; eam0.w = ea_sum[3] * invE;
    eam1.x = ea_sum[4] * invE; eam1.y = ea_sum[5] * invE;
    eam1.z = ea_sum[6] * invE; eam1.w = ea_sum[7] * invE;
    uint4 eamp = pack8_half(eam0, eam1);

    int beg = off[node], end = off[node + 1];
    float sumw = 0.f;
    float4 acc = make_float4(0.f, 0.f, 0.f, 0.f);

    int cb = beg;
    while (cb < end) {
        int cnt = end - cb; if (cnt > 64) cnt = 64;
        int sl = 0;
        uint4 pea = eamp;
        if (lane < cnt) {
            sl = csr_src[cb + lane];
            int el = csr_eid[cb + lane];
            if (el < E) pea = *(const uint4*)(eah + (size_t)el * 8);
        }
        int nit = (cnt + 3) >> 2;
        float2 r0, r1;
        {
            int s0 = __shfl(sl, seg, 64);
            r0 = *(const float2*)(xl2h + (size_t)s0 * 64 + c4);
            int s1 = __shfl(sl, (seg + 4) & 63, 64);
            r1 = *(const float2*)(xl2h + (size_t)s1 * 64 + c4);
        }
        for (int it = 0; it < nit; ++it) {
            int jj = it * 4 + seg;
            float2 cur = r0;
            r0 = r1;
            {
                int sn = __shfl(sl, (jj + 8) & 63, 64);
                r1 = *(const float2*)(xl2h + (size_t)sn * 64 + c4);
            }
            int ex = __shfl((int)pea.x, jj, 64);
            int ey = __shfl((int)pea.y, jj, 64);
            int ez = __shfl((int)pea.z, jj, 64);
            int ew = __shfl((int)pea.w, jj, 64);
            float eav[8];
            unpack8_half(ex, ey, ez, ew, eav);
            const __half2* hp = (const __half2*)&cur;
            float2 lo = __half22float2(hp[0]);
            float2 hi = __half22float2(hp[1]);
            float4 xs = make_float4(lo.x, lo.y, hi.x, hi.y);
            float4 ee = make_float4(0.f, 0.f, 0.f, 0.f);
#pragma unroll
            for (int k = 0; k < 8; k++) {
                ee.x += eav[k] * we[k].x; ee.y += eav[k] * we[k].y;
                ee.z += eav[k] * we[k].z; ee.w += eav[k] * we[k].w;
            }
            float4 v;
            v.x = xs.x + xr4.x + ee.x; v.y = xs.y + xr4.y + ee.y;
            v.z = xs.z + xr4.z + ee.z; v.w = xs.w + xr4.w + ee.w;
            v.x = v.x > 0.f ? v.x : 0.2f * v.x;
            v.y = v.y > 0.f ? v.y : 0.2f * v.y;
            v.z = v.z > 0.f ? v.z : 0.2f * v.z;
            v.w = v.w > 0.f ? v.w : 0.2f * v.w;
            float p = v.x * at4.x + v.y * at4.y + v.z * at4.z + v.w * at4.w;
            p += __shfl_xor(p, 1, 64);
            p += __shfl_xor(p, 2, 64);
            p += __shfl_xor(p, 4, 64);
            p += __shfl_xor(p, 8, 64);        // 16-lane segment reduce
            bool valid = jj < cnt;
            float wgt = valid ? expf(p) : 0.f;
            acc.x += wgt * xs.x;
            acc.y += wgt * xs.y;
            acc.z += wgt * xs.z;
            acc.w += wgt * xs.w;
            sumw += wgt;
        }
        cb += cnt;
    }
#pragma unroll
    for (int d = 16; d <= 32; d <<= 1) {
        acc.x += __shfl_xor(acc.x, d, 64);
        acc.y += __shfl_xor(acc.y, d, 64);
        acc.z += __shfl_xor(acc.z, d, 64);
        acc.w += __shfl_xor(acc.w, d, 64);
        sumw  += __shfl_xor(sumw, d, 64);
    }
    float inv = 1.f / (sumw + 1e-16f);
    float4 bi = *(const float4*)(bias2 + c4);
    float4 g4 = *(const float4*)(g + c4);
    float4 b4 = *(const float4*)(bb_ + c4);
    float4 m4 = *(const float4*)(mm_ + c4);
    float4 v4 = *(const float4*)(vv_ + c4);
    float4 o;
    o.x = acc.x * inv + bi.x; o.y = acc.y * inv + bi.y;
    o.z = acc.z * inv + bi.z; o.w = acc.w * inv + bi.w;
    o.x = (o.x - m4.x) * rsqrtf(v4.x + 1e-5f) * g4.x + b4.x;
    o.y = (o.y - m4.y) * rsqrtf(v4.y + 1e-5f) * g4.y + b4.y;
    o.z = (o.z - m4.z) * rsqrtf(v4.z + 1e-5f) * g4.z + b4.z;
    o.w = (o.w - m4.w) * rsqrtf(v4.w + 1e-5f) * g4.w + b4.w;
    if (seg == 0) {
        o.x = elu_f(o.x); o.y = elu_f(o.y); o.z = elu_f(o.z); o.w = elu_f(o.w);
        *(uint2*)(h2h + (size_t)node * 64 + c4) = f4_to_half4(o);
    }
}

// ---------- u = h2@Wm1[0:64], v = h2@Wm1[64:128]  (fp16 out, no bias) ----------
__global__ __launch_bounds__(256) void k_uv(const __half* __restrict__ h2h, const float* __restrict__ Wm1,
                                            __half* __restrict__ uh, __half* __restrict__ vh, int N) {
    __shared__ float sh[32][32];    // [kk][node]
    __shared__ float sw[32][128];   // [kk][col]  (u cols 0..63, v cols 64..127)
    int t = threadIdx.x;
    int tr = t >> 5, tc = t & 31;
    int n0 = blockIdx.x * 32;
    float acc[4][4];
#pragma unroll
    for (int i = 0; i < 4; i++)
#pragma unroll
        for (int j = 0; j < 4; j++) acc[i][j] = 0.f;
    for (int k0 = 0; k0 < 64; k0 += 32) {
        {
            int n = t >> 3, kk0 = (t & 7) * 4;
            int gn = n0 + n;
            float4 hv = make_float4(0.f, 0.f, 0.f, 0.f);
            if (gn < N) hv = half4_to_f4(*(const uint2*)(h2h + (size_t)gn * 64 + k0 + kk0));
            sh[kk0 + 0][n] = hv.x; sh[kk0 + 1][n] = hv.y; sh[kk0 + 2][n] = hv.z; sh[kk0 + 3][n] = hv.w;
        }
        for (int i = t; i < 32 * 128; i += 256) {
            int kk = i >> 7, c = i & 127;
            sw[kk][c] = (c < 64) ? Wm1[(size_t)(k0 + kk) * 64 + c]
                                 : Wm1[(size_t)(64 + k0 + kk) * 64 + (c - 64)];
        }
        __syncthreads();
#pragma unroll
        for (int kk = 0; kk < 32; kk++) {
            float4 hv = *(const float4*)&sh[kk][tr * 4];
            float4 wv = *(const float4*)&sw[kk][tc * 4];
            float hh[4] = { hv.x, hv.y, hv.z, hv.w };
            float wwv[4] = { wv.x, wv.y, wv.z, wv.w };
#pragma unroll
            for (int i = 0; i < 4; i++)
#pragma unroll
                for (int j = 0; j < 4; j++) acc[i][j] += hh[i] * wwv[j];
        }
        __syncthreads();
    }
#pragma unroll
    for (int i = 0; i < 4; i++) {
        int gn = n0 + tr * 4 + i;
        if (gn >= N) continue;
#pragma unroll
        for (int j = 0; j < 4; j++) {
            int c = tc * 4 + j;
            if (c < 64) uh[(size_t)gn * 64 + c] = __float2half(acc[i][j]);
            else        vh[(size_t)gn * 64 + (c - 64)] = __float2half(acc[i][j]);
        }
    }
}

// ---------- edge MLP head v3: inline weA (fp16 ea); z1 = gelu(u[r]+v[c]+weA); layer2+3 fused ----------
__global__ __launch_bounds__(256) void k_mlp2(const __half* __restrict__ uh, const __half* __restrict__ vh,
                                              const __half* __restrict__ eah, const int* __restrict__ ei,
                                              const float* __restrict__ Wm1, const float* __restrict__ bm1,
                                              const float* __restrict__ Wm2, const float* __restrict__ bm2,
                                              const float* __restrict__ Wm3, const float* __restrict__ bm3,
                                              float* __restrict__ out, int E) {
    __shared__ float sw2[64 * 32];
    __shared__ float sW1e[8 * 64];
    __shared__ float sb1[64];
    __shared__ int sre[64], sce[64];
    __shared__ float z1[64 * 68];
    int t = threadIdx.x;
    for (int i = t; i < 64 * 32; i += 256) sw2[i] = Wm2[i];
    for (int i = t; i < 512; i += 256) sW1e[i] = Wm1[128 * 64 + i];
    if (t < 64) sb1[t] = bm1[t];
    int e0 = blockIdx.x * 64;
    if (t < 64) {
        int e = e0 + t;
        if (e < E) { sre[t] = ei[e]; sce[t] = ei[E + e]; }
        else { sre[t] = 0; sce[t] = 0; }
    }
    __syncthreads();
    for (int i = t; i < 512; i += 256) {
        int el = i >> 3, q = i & 7;
        int r = sre[el], c = sce[el];
        uint4 ru = *(const uint4*)(uh + (size_t)r * 64 + q * 8);
        uint4 rv = *(const uint4*)(vh + (size_t)c * 64 + q * 8);
        uint4 rea = *(const uint4*)(eah + (size_t)(e0 + el) * 8);
        float av[8];
        unpack8_half((int)rea.x, (int)rea.y, (int)rea.z, (int)rea.w, av);
        float wv[8];
#pragma unroll
        for (int j = 0; j < 8; j++) wv[j] = sb1[q * 8 + j];
#pragma unroll
        for (int k = 0; k < 8; k++) {
            float a = av[k];
#pragma unroll
            for (int j = 0; j < 8; j++) wv[j] += a * sW1e[k * 64 + q * 8 + j];
        }
        float4 uhi, vhi;
        float4 ulo = half8_lo_hi(ru, &uhi);
        float4 vlo = half8_lo_hi(rv, &vhi);
        float4 zlo, zhi;
        zlo.x = gelu_f(ulo.x + vlo.x + wv[0]);
        zlo.y = gelu_f(ulo.y + vlo.y + wv[1]);
        zlo.z = gelu_f(ulo.z + vlo.z + wv[2]);
        zlo.w = gelu_f(ulo.w + vlo.w + wv[3]);
        zhi.x = gelu_f(uhi.x + vhi.x + wv[4]);
        zhi.y = gelu_f(uhi.y + vhi.y + wv[5]);
        zhi.z = gelu_f(uhi.z + vhi.z + wv[6]);
        zhi.w = gelu_f(uhi.w + vhi.w + wv[7]);
        *(float4*)(z1 + el * 68 + q * 8)     = zlo;
        *(float4*)(z1 + el * 68 + q * 8 + 4) = zhi;
    }
    __syncthreads();
    int tr = t >> 3;
    int tc = t & 7;
    float b2[4], w3[4];
#pragma unroll
    for (int j = 0; j < 4; j++) { b2[j] = bm2[tc * 4 + j]; w3[j] = Wm3[tc * 4 + j]; }
    float b3 = bm3[0];
    float acc0[4], acc1[4];
#pragma unroll
    for (int j = 0; j < 4; j++) { acc0[j] = 0.f; acc1[j] = 0.f; }
    const float* z0p = z1 + (tr * 2 + 0) * 68;
    const float* z1p = z1 + (tr * 2 + 1) * 68;
#pragma unroll 8
    for (int k = 0; k < 64; k++) {
        float4 wv = *(const float4*)(sw2 + k * 32 + tc * 4);
        float a0 = z0p[k];
        float a1 = z1p[k];
        acc0[0] += a0 * wv.x; acc0[1] += a0 * wv.y; acc0[2] += a0 * wv.z; acc0[3] += a0 * wv.w;
        acc1[0] += a1 * wv.x; acc1[1] += a1 * wv.y; acc1[2] += a1 * wv.z; acc1[3] += a1 * wv.w;
    }
    float p0 = 0.f, p1 = 0.f;
#pragma unroll
    for (int j = 0; j < 4; j++) {
        p0 += gelu_f(acc0[j] + b2[j]) * w3[j];
        p1 += gelu_f(acc1[j] + b2[j]) * w3[j];
    }
    p0 += __shfl_xor(p0, 1, 64); p0 += __shfl_xor(p0, 2, 64); p0 += __shfl_xor(p0, 4, 64);
    p1 += __shfl_xor(p1, 1, 64); p1 += __shfl_xor(p1, 2, 64); p1 += __shfl_xor(p1, 4, 64);
    if (tc == 0) {
        int e = e0 + tr * 2;
        if (e < E)     out[e]     = 1.f / (1.f + expf(-(p0 + b3)));
        if (e + 1 < E) out[e + 1] = 1.f / (1.f + expf(-(p1 + b3)));
    }
}

extern "C" void kernel_launch(void* const* d_in, const int* in_sizes, int n_in,
                              void* d_out, int out_size, void* d_ws, size_t ws_size,
                              hipStream_t stream) {
    const float* x    = (const float*)d_in[0];
    const int*   ei   = (const int*)d_in[1];
    const float* ea   = (const float*)d_in[2];
    const float* Wl1  = (const float*)d_in[3];
    const float* bl1  = (const float*)d_in[4];
    const float* Wr1  = (const float*)d_in[5];
    const float* br1  = (const float*)d_in[6];
    const float* We1  = (const float*)d_in[7];
    const float* att1 = (const float*)d_in[8];
    const float* bias1= (const float*)d_in[9];
    const float* Wl2  = (const float*)d_in[10];
    const float* bl2  = (const float*)d_in[11];
    const float* Wr2  = (const float*)d_in[12];
    const float* br2  = (const float*)d_in[13];
    const float* We2  = (const float*)d_in[14];
    const float* att2 = (const float*)d_in[15];
    const float* bias2= (const float*)d_in[16];
    const float* bn1g = (const float*)d_in[17];
    const float* bn1b = (const float*)d_in[18];
    const float* bn1m = (const float*)d_in[19];
    const float* bn1v = (const float*)d_in[20];
    const float* bn2g = (const float*)d_in[21];
    const float* bn2b = (const float*)d_in[22];
    const float* bn2m = (const float*)d_in[23];
    const float* bn2v = (const float*)d_in[24];
    const float* Wres = (const float*)d_in[25];
    const float* Wm1  = (const float*)d_in[26];
    const float* bm1  = (const float*)d_in[27];
    const float* Wm2  = (const float*)d_in[28];
    const float* bm2  = (const float*)d_in[29];
    const float* Wm3  = (const float*)d_in[30];
    const float* bm3  = (const float*)d_in[31];
    float* out = (float*)d_out;
    float* ws = (float*)d_ws;

    const int N = NN, E = EE, Etot = ETOT;

    // workspace layout (floats)
    float* ea_sum   = ws;                                     // 16
    int*   counts   = (int*)(ws + 16);                        // N
    int*   off      = (int*)(ws + 16 + (size_t)N);            // N+16
    int*   cursor   = (int*)(ws + 32 + (size_t)2 * N);        // N
    int*   csr_src  = (int*)(ws + 32 + (size_t)3 * N);        // Etot
    int*   csr_eid  = (int*)(ws + 32 + (size_t)3 * N + Etot); // Etot
    size_t base     = 32 + (size_t)3 * N + (size_t)2 * Etot;
    __half* xl1h    = (__half*)(ws + base);                   // 256N halfs = 128N floats
    __half* xl2h    = xl1h;                                   // reuses (xl1h dead after k_fagg1)
    __half* h2h     = (__half*)(ws + base + (size_t)128 * N); // 64N halfs = 32N floats
    __half* xr1h    = (__half*)(ws + base + (size_t)160 * N); // 256N halfs = 128N floats
    __half* h1h     = xr1h;                                   // in-place (own row read before write)
    __half* xr2h    = (__half*)(ws + base + (size_t)288 * N); // 64N halfs = 32N floats
    __half* uh      = xr2h;                                   // overlays xr2h (dead after k_fagg2)
    __half* vh      = uh + (size_t)64 * N;                    // next 32N floats
    __half* eah     = (__half*)(ws + base + (size_t)352 * N); // 8E halfs = 4E floats

    hipMemsetAsync(ea_sum, 0, 16 * sizeof(float), stream);
    hipMemsetAsync(counts, 0, (size_t)N * sizeof(int), stream);

    int S = (Etot + 255) / 256;
    k_init<<<256 + S, 256, 0, stream>>>(ea, ea_sum, eah, ei, counts, E, N);
    k_scan<<<1, 1024, 0, stream>>>(counts, off, cursor, N);
    k_scat_nt1<<<S + (N + 31) / 32, 256, 0, stream>>>(ei, cursor, csr_src, csr_eid,
                                                      x, Wl1, bl1, Wr1, br1, xl1h, xr1h, E, N);
    k_fagg1<<<(N + 3) / 4, 256, 0, stream>>>(xl1h, xr1h, off, csr_src, csr_eid, eah, ea_sum,
                                             We1, att1, bias1, x, Wres,
                                             bn1g, bn1b, bn1m, bn1v, h1h, E, N);
    k_xlr2<<<(N + 31) / 32, 256, 0, stream>>>(h1h, Wl2, bl2, Wr2, br2, xl2h, xr2h, N);
    k_fagg2<<<(N + 3) / 4, 256, 0, stream>>>(xl2h, xr2h, off, csr_src, csr_eid, eah, ea_sum,
                                             We2, att2, bias2,
                                             bn2g, bn2b, bn2m, bn2v, h2h, E, N);
    k_uv<<<(N + 31) / 32, 256, 0, stream>>>(h2h, Wm1, uh, vh, N);
    k_mlp2<<<(E + 63) / 64, 256, 0, stream>>>(uh, vh, eah, ei, Wm1, bm1, Wm2, bm2, Wm3, bm3, out, E);
}

// Round 18
// 452.192 us; speedup vs baseline: 1.0649x; 1.0649x over previous
//
#include <hip/hip_runtime.h>
#include <hip/hip_bf16.h>
#include <hip/hip_fp16.h>
#include <math.h>

#define NN 50000
#define EE 400000
#define ETOT (NN + EE)

// ---------- helpers ----------
__device__ __forceinline__ float gelu_f(float x) {
    return 0.5f * x * (1.f + erff(x * 0.7071067811865476f));
}
__device__ __forceinline__ float elu_f(float x) {
    return x > 0.f ? x : expm1f(x);
}
__device__ __forceinline__ float4 half8_lo_hi(uint4 raw, float4* hi) {
    __half2 h0 = *(__half2*)&raw.x, h1 = *(__half2*)&raw.y;
    __half2 h2 = *(__half2*)&raw.z, h3 = *(__half2*)&raw.w;
    float2 f0 = __half22float2(h0), f1 = __half22float2(h1);
    float2 f2 = __half22float2(h2), f3 = __half22float2(h3);
    *hi = make_float4(f2.x, f2.y, f3.x, f3.y);
    return make_float4(f0.x, f0.y, f1.x, f1.y);
}
__device__ __forceinline__ float4 half4_to_f4(uint2 raw) {
    __half2 a = *(__half2*)&raw.x, b = *(__half2*)&raw.y;
    float2 fa = __half22float2(a), fb = __half22float2(b);
    return make_float4(fa.x, fa.y, fb.x, fb.y);
}
__device__ __forceinline__ uint2 f4_to_half4(float4 v) {
    __half2 h0 = __floats2half2_rn(v.x, v.y);
    __half2 h1 = __floats2half2_rn(v.z, v.w);
    uint2 pk;
    pk.x = *(unsigned*)&h0;
    pk.y = *(unsigned*)&h1;
    return pk;
}
__device__ __forceinline__ uint4 pack8_half(float4 a, float4 b) {
    __half2 q0 = __floats2half2_rn(a.x, a.y), q1 = __floats2half2_rn(a.z, a.w);
    __half2 q2 = __floats2half2_rn(b.x, b.y), q3 = __floats2half2_rn(b.z, b.w);
    uint4 pk;
    pk.x = *(unsigned*)&q0; pk.y = *(unsigned*)&q1;
    pk.z = *(unsigned*)&q2; pk.w = *(unsigned*)&q3;
    return pk;
}
__device__ __forceinline__ void unpack8_half(int x, int y, int z, int w, float* ev) {
    float2 f0 = __half22float2(*(__half2*)&x);
    float2 f1 = __half22float2(*(__half2*)&y);
    float2 f2 = __half22float2(*(__half2*)&z);
    float2 f3 = __half22float2(*(__half2*)&w);
    ev[0] = f0.x; ev[1] = f0.y; ev[2] = f1.x; ev[3] = f1.y;
    ev[4] = f2.x; ev[5] = f2.y; ev[6] = f3.x; ev[7] = f3.y;
}

// ---------- combined: ea mean (sum) + ea->fp16 copy [blocks 0..255] + degree count [blocks 256..] ----------
__global__ __launch_bounds__(256) void k_init(const float* __restrict__ ea, float* __restrict__ ea_sum,
                                              __half* __restrict__ eah,
                                              const int* __restrict__ ei, int* __restrict__ counts,
                                              int E, int N) {
    int t = threadIdx.x;
    if (blockIdx.x < 256) {
        float s[8];
#pragma unroll
        for (int i = 0; i < 8; i++) s[i] = 0.f;
        for (int e = blockIdx.x * 256 + t; e < E; e += 256 * 256) {
            const float4* p = (const float4*)(ea + (size_t)e * 8);
            float4 a = p[0], b = p[1];
            s[0] += a.x; s[1] += a.y; s[2] += a.z; s[3] += a.w;
            s[4] += b.x; s[5] += b.y; s[6] += b.z; s[7] += b.w;
            *(uint4*)(eah + (size_t)e * 8) = pack8_half(a, b);
        }
#pragma unroll
        for (int o = 32; o; o >>= 1)
#pragma unroll
            for (int i = 0; i < 8; i++) s[i] += __shfl_xor(s[i], o, 64);
        __shared__ float sh[4][8];
        int lane = t & 63, w = t >> 6;
        if (lane == 0)
#pragma unroll
            for (int i = 0; i < 8; i++) sh[w][i] = s[i];
        __syncthreads();
        if (t < 8) {
            float v = sh[0][t] + sh[1][t] + sh[2][t] + sh[3][t];
            atomicAdd(ea_sum + t, v);
        }
    } else {
        int e = (blockIdx.x - 256) * 256 + t;
        if (e >= E + N) return;
        int d = (e < E) ? ei[E + e] : (e - E);
        atomicAdd(counts + d, 1);
    }
}

// ---------- scan (4 elems/thread) ----------
__global__ __launch_bounds__(1024) void k_scan(const int* __restrict__ counts, int* __restrict__ off,
                                               int* __restrict__ cursor, int N) {
    __shared__ int buf[1024];
    int t = threadIdx.x;
    int carry = 0;
    if (t == 0) off[0] = 0;
    for (int base = 0; base < N; base += 4096) {
        int i0 = base + t * 4;
        int v0 = 0, v1 = 0, v2 = 0, v3 = 0;
        if (i0 + 3 < N) {
            int4 vv = *(const int4*)(counts + i0);
            v0 = vv.x; v1 = vv.y; v2 = vv.z; v3 = vv.w;
        } else {
            if (i0 < N)     v0 = counts[i0];
            if (i0 + 1 < N) v1 = counts[i0 + 1];
            if (i0 + 2 < N) v2 = counts[i0 + 2];
            if (i0 + 3 < N) v3 = counts[i0 + 3];
        }
        int s01 = v0 + v1, s012 = s01 + v2, tot4 = s012 + v3;
        buf[t] = tot4;
        __syncthreads();
        for (int o = 1; o < 1024; o <<= 1) {
            int add = (t >= o) ? buf[t - o] : 0;
            __syncthreads();
            buf[t] += add;
            __syncthreads();
        }
        int incl4 = buf[t] + carry;
        int excl = incl4 - tot4;
        if (i0 < N)     { off[i0 + 1] = excl + v0;   cursor[i0]     = excl; }
        if (i0 + 1 < N) { off[i0 + 2] = excl + s01;  cursor[i0 + 1] = excl + v0; }
        if (i0 + 2 < N) { off[i0 + 3] = excl + s012; cursor[i0 + 2] = excl + s01; }
        if (i0 + 3 < N) { off[i0 + 4] = excl + tot4; cursor[i0 + 3] = excl + s012; }
        int tot = buf[1023];
        __syncthreads();
        carry += tot;
    }
}

// ---------- combined: scatter [blocks 0..S) + ntrans1 [blocks S..) ----------
__global__ __launch_bounds__(256) void k_scat_nt1(const int* __restrict__ ei, int* __restrict__ cursor,
                                                  int* __restrict__ csr_src, int* __restrict__ csr_eid,
                                                  const float* __restrict__ x,
                                                  const float* __restrict__ Wl, const float* __restrict__ bl,
                                                  const float* __restrict__ Wr, const float* __restrict__ br,
                                                  __half* __restrict__ xl1h, __half* __restrict__ xr1h,
                                                  int E, int N) {
    __shared__ float swl[16 * 256];
    __shared__ float swr[16 * 256];
    __shared__ float sx[32 * 16];
    int t = threadIdx.x;
    int S = (E + N + 255) >> 8;
    if ((int)blockIdx.x < S) {
        int e = blockIdx.x * 256 + t;
        if (e >= E + N) return;
        int s, d;
        if (e < E) { s = ei[e]; d = ei[E + e]; }
        else { s = d = e - E; }
        int pos = atomicAdd(cursor + d, 1);
        csr_src[pos] = s;
        csr_eid[pos] = e;
        return;
    }
    int bid = blockIdx.x - S;
#pragma unroll
    for (int k = 0; k < 16; k++) { swl[k * 256 + t] = Wl[k * 256 + t]; swr[k * 256 + t] = Wr[k * 256 + t]; }
    int n0 = bid * 32;
    for (int i = t; i < 32 * 16; i += 256) {
        int n = n0 + (i >> 4);
        sx[i] = (n < N) ? x[(size_t)n * 16 + (i & 15)] : 0.f;
    }
    __syncthreads();
    float bL = bl[t], bR = br[t];
    for (int ni = 0; ni < 32; ni++) {
        int n = n0 + ni;
        if (n >= N) break;
        float al = bL, ar = bR;
#pragma unroll
        for (int k = 0; k < 16; k++) {
            float xv = sx[ni * 16 + k];
            al += xv * swl[k * 256 + t];
            ar += xv * swr[k * 256 + t];
        }
        xl1h[(size_t)n * 256 + t] = __float2half(al);
        xr1h[(size_t)n * 256 + t] = __float2half(ar);
    }
}

// ---------- fused conv1: zero-LDS, packed-ea broadcast (4 shfl), depth-3 prefetch, no-shift softmax ----------
__global__ __launch_bounds__(256) void k_fagg1(const __half* __restrict__ xl1h, const __half* __restrict__ xr1h,
                                               const int* __restrict__ off, const int* __restrict__ csr_src,
                                               const int* __restrict__ csr_eid,
                                               const __half* __restrict__ eah, const float* __restrict__ ea_sum,
                                               const float* __restrict__ We1, const float* __restrict__ att1,
                                               const float* __restrict__ bias1,
                                               const float* __restrict__ x, const float* __restrict__ Wres,
                                               const float* __restrict__ g, const float* __restrict__ bb_,
                                               const float* __restrict__ mm_, const float* __restrict__ vv_,
                                               __half* __restrict__ h1h,
                                               int E, int N) {
    int t = threadIdx.x;
    int lane = t & 63, w = t >> 6;
    int node = blockIdx.x * 4 + w;
    if (node >= N) return;
    int c4 = lane * 4;
    float4 we[8];
#pragma unroll
    for (int k = 0; k < 8; k++) we[k] = *(const float4*)(We1 + k * 256 + c4);
    float4 xr4 = half4_to_f4(*(const uint2*)(xr1h + (size_t)node * 256 + c4));
    float4 at4 = *(const float4*)(att1 + c4);
    float invE = 1.f / (float)E;
    float4 eam0, eam1;
    eam0.x = ea_sum[0] * invE; eam0.y = ea_sum[1] * invE;
    eam0.z = ea_sum[2] * invE; eam0.w = ea_sum[3] * invE;
    eam1.x = ea_sum[4] * invE; eam1.y = ea_sum[5] * invE;
    eam1.z = ea_sum[6] * invE; eam1.w = ea_sum[7] * invE;
    uint4 eamp = pack8_half(eam0, eam1);

    int beg = off[node], end = off[node + 1];
    float sumw = 0.f;
    float4 acc = make_float4(0.f, 0.f, 0.f, 0.f);

    int cb = beg;
    while (cb < end) {
        int cnt = end - cb; if (cnt > 64) cnt = 64;
        int sl = 0;
        uint4 pea = eamp;
        if (lane < cnt) {
            sl = csr_src[cb + lane];
            int el = csr_eid[cb + lane];
            if (el < E) pea = *(const uint4*)(eah + (size_t)el * 8);
        }
        float2 r0 = make_float2(0.f, 0.f), r1 = r0, r2 = r0;
        {
            int s0 = __shfl(sl, 0, 64);
            r0 = *(const float2*)(xl1h + (size_t)s0 * 256 + c4);
            if (cnt > 1) { int s1 = __shfl(sl, 1, 64); r1 = *(const float2*)(xl1h + (size_t)s1 * 256 + c4); }
            if (cnt > 2) { int s2 = __shfl(sl, 2, 64); r2 = *(const float2*)(xl1h + (size_t)s2 * 256 + c4); }
        }
        for (int j = 0; j < cnt; j++) {
            float2 cur = r0;
            r0 = r1; r1 = r2;
            if (j + 3 < cnt) {
                int s3 = __shfl(sl, j + 3, 64);
                r2 = *(const float2*)(xl1h + (size_t)s3 * 256 + c4);
            }
            int ex = __shfl((int)pea.x, j, 64);
            int ey = __shfl((int)pea.y, j, 64);
            int ez = __shfl((int)pea.z, j, 64);
            int ew = __shfl((int)pea.w, j, 64);
            float eav[8];
            unpack8_half(ex, ey, ez, ew, eav);
            const __half2* hp = (const __half2*)&cur;
            float2 lo = __half22float2(hp[0]);
            float2 hi = __half22float2(hp[1]);
            float4 xs = make_float4(lo.x, lo.y, hi.x, hi.y);
            float4 ee = make_float4(0.f, 0.f, 0.f, 0.f);
#pragma unroll
            for (int k = 0; k < 8; k++) {
                ee.x += eav[k] * we[k].x; ee.y += eav[k] * we[k].y;
                ee.z += eav[k] * we[k].z; ee.w += eav[k] * we[k].w;
            }
            float4 v;
            v.x = xs.x + xr4.x + ee.x; v.y = xs.y + xr4.y + ee.y;
            v.z = xs.z + xr4.z + ee.z; v.w = xs.w + xr4.w + ee.w;
            v.x = v.x > 0.f ? v.x : 0.2f * v.x;
            v.y = v.y > 0.f ? v.y : 0.2f * v.y;
            v.z = v.z > 0.f ? v.z : 0.2f * v.z;
            v.w = v.w > 0.f ? v.w : 0.2f * v.w;
            float p = v.x * at4.x + v.y * at4.y + v.z * at4.z + v.w * at4.w;
            p += __shfl_xor(p, 1, 64);
            p += __shfl_xor(p, 2, 64);
            p += __shfl_xor(p, 4, 64);
            p += __shfl_xor(p, 8, 64);
            float wgt = expf(p);
            acc.x += wgt * xs.x;
            acc.y += wgt * xs.y;
            acc.z += wgt * xs.z;
            acc.w += wgt * xs.w;
            sumw += wgt;
        }
        cb += cnt;
    }
    float inv = 1.f / (sumw + 1e-16f);
    float4 r = make_float4(0.f, 0.f, 0.f, 0.f);
#pragma unroll
    for (int q = 0; q < 4; q++) {
        float4 xq = *(const float4*)(x + (size_t)node * 16 + q * 4);
        float xa[4] = { xq.x, xq.y, xq.z, xq.w };
#pragma unroll
        for (int kk = 0; kk < 4; kk++) {
            float4 wv = *(const float4*)(Wres + (size_t)(q * 4 + kk) * 256 + c4);
            r.x += xa[kk] * wv.x; r.y += xa[kk] * wv.y;
            r.z += xa[kk] * wv.z; r.w += xa[kk] * wv.w;
        }
    }
    float4 bi = *(const float4*)(bias1 + c4);
    float4 g4 = *(const float4*)(g + c4);
    float4 b4 = *(const float4*)(bb_ + c4);
    float4 m4 = *(const float4*)(mm_ + c4);
    float4 v4 = *(const float4*)(vv_ + c4);
    float4 o;
    o.x = acc.x * inv + bi.x; o.y = acc.y * inv + bi.y;
    o.z = acc.z * inv + bi.z; o.w = acc.w * inv + bi.w;
    o.x = (o.x - m4.x) * rsqrtf(v4.x + 1e-5f) * g4.x + b4.x + r.x;
    o.y = (o.y - m4.y) * rsqrtf(v4.y + 1e-5f) * g4.y + b4.y + r.y;
    o.z = (o.z - m4.z) * rsqrtf(v4.z + 1e-5f) * g4.z + b4.z + r.z;
    o.w = (o.w - m4.w) * rsqrtf(v4.w + 1e-5f) * g4.w + b4.w + r.w;
    o.x = elu_f(o.x); o.y = elu_f(o.y); o.z = elu_f(o.z); o.w = elu_f(o.w);
    *(uint2*)(h1h + (size_t)node * 256 + c4) = f4_to_half4(o);
}

// ---------- xl2(fp16) = h1@Wl2+bl2, xr2(fp16) = h1@Wr2+br2 (h1 fp16 in) ----------
__global__ __launch_bounds__(256) void k_xlr2(const __half* __restrict__ h1h,
                                              const float* __restrict__ Wl2, const float* __restrict__ bl2,
                                              const float* __restrict__ Wr2, const float* __restrict__ br2,
                                              __half* __restrict__ xl2h, __half* __restrict__ xr2h, int N) {
    __shared__ float sh[32][32];    // [kk][node]
    __shared__ float sw[32][128];   // [kk][col]
    int t = threadIdx.x;
    int tr = t >> 5, tc = t & 31;
    int n0 = blockIdx.x * 32;
    float acc[4][4];
#pragma unroll
    for (int i = 0; i < 4; i++)
#pragma unroll
        for (int j = 0; j < 4; j++) acc[i][j] = 0.f;
    for (int k0 = 0; k0 < 256; k0 += 32) {
        {
            int n = t >> 3, kk0 = (t & 7) * 4;
            int gn = n0 + n;
            float4 hv = make_float4(0.f, 0.f, 0.f, 0.f);
            if (gn < N) hv = half4_to_f4(*(const uint2*)(h1h + (size_t)gn * 256 + k0 + kk0));
            sh[kk0 + 0][n] = hv.x; sh[kk0 + 1][n] = hv.y; sh[kk0 + 2][n] = hv.z; sh[kk0 + 3][n] = hv.w;
        }
        for (int i = t; i < 32 * 128; i += 256) {
            int kk = i >> 7, c = i & 127;
            sw[kk][c] = (c < 64) ? Wl2[(size_t)(k0 + kk) * 64 + c] : Wr2[(size_t)(k0 + kk) * 64 + (c - 64)];
        }
        __syncthreads();
#pragma unroll
        for (int kk = 0; kk < 32; kk++) {
            float4 hv = *(const float4*)&sh[kk][tr * 4];
            float4 wv = *(const float4*)&sw[kk][tc * 4];
            float hh[4] = { hv.x, hv.y, hv.z, hv.w };
            float wwv[4] = { wv.x, wv.y, wv.z, wv.w };
#pragma unroll
            for (int i = 0; i < 4; i++)
#pragma unroll
                for (int j = 0; j < 4; j++) acc[i][j] += hh[i] * wwv[j];
        }
        __syncthreads();
    }
#pragma unroll
    for (int i = 0; i < 4; i++) {
        int gn = n0 + tr * 4 + i;
        if (gn >= N) continue;
#pragma unroll
        for (int j = 0; j < 4; j++) {
            int c = tc * 4 + j;
            float vv = acc[i][j];
            if (c < 64) xl2h[(size_t)gn * 64 + c] = __float2half(vv + bl2[c]);
            else        xr2h[(size_t)gn * 64 + (c - 64)] = __float2half(vv + br2[c - 64]);
        }
    }
}

// ---------- fused conv2 v3: 4 edges/wave, packed-ea broadcast, no-shift softmax ----------
__global__ __launch_bounds__(256) void k_fagg2(const __half* __restrict__ xl2h, const __half* __restrict__ xr2h,
                                               const int* __restrict__ off, const int* __restrict__ csr_src,
                                               const int* __restrict__ csr_eid,
                                               const __half* __restrict__ eah, const float* __restrict__ ea_sum,
                                               const float* __restrict__ We2, const float* __restrict__ att2,
                                               const float* __restrict__ bias2,
                                               const float* __restrict__ g, const float* __restrict__ bb_,
                                               const float* __restrict__ mm_, const float* __restrict__ vv_,
                                               __half* __restrict__ h2h,
                                               int E, int N) {
    int t = threadIdx.x;
    int lane = t & 63, w = t >> 6;
    int node = blockIdx.x * 4 + w;
    if (node >= N) return;
    int seg = lane >> 4;          // edge slot 0..3
    int c4 = (lane & 15) * 4;     // 4 channels owned
    float4 we[8];
#pragma unroll
    for (int k = 0; k < 8; k++) we[k] = *(const float4*)(We2 + k * 64 + c4);
    float4 xr4 = half4_to_f4(*(const uint2*)(xr2h + (size_t)node * 64 + c4));
    float4 at4 = *(const float4*)(att2 + c4);
    float invE = 1.f / (float)E;
    float4 eam0, eam1;
    eam0.x = ea_sum[0] * invE; eam0.y = ea_sum[1] * invE;
    eam0.z = ea_sum[2] * invE; eam0.w = ea_sum[3] * invE;
    eam1.x = ea_sum[4] * invE; eam1.y = ea_sum[5] * invE;
    eam1.z = ea_sum[6] * invE; eam1.w = ea_sum[7] * invE;
    uint4 eamp = pack8_half(eam0, eam1);

    int beg = off[node], end = off[node + 1];
    float sumw = 0.f;
    float4 acc = make_float4(0.f, 0.f, 0.f, 0.f);

    int cb = beg;
    while (cb < end) {
        int cnt = end - cb; if (cnt > 64) cnt = 64;
        int sl = 0;
        uint4 pea = eamp;
        if (lane < cnt) {
            sl = csr_src[cb + lane];
            int el = csr_eid[cb + lane];
            if (el < E) pea = *(const uint4*)(eah + (size_t)el * 8);
        }
        int nit = (cnt + 3) >> 2;
        float2 r0, r1;
        {
            int s0 = __shfl(sl, seg, 64);
            r0 = *(const float2*)(xl2h + (size_t)s0 * 64 + c4);
            int s1 = __shfl(sl, (seg + 4) & 63, 64);
            r1 = *(const float2*)(xl2h + (size_t)s1 * 64 + c4);
        }
        for (int it = 0; it < nit; ++it) {
            int jj = it * 4 + seg;
            float2 cur = r0;
            r0 = r1;
            {
                int sn = __shfl(sl, (jj + 8) & 63, 64);
                r1 = *(const float2*)(xl2h + (size_t)sn * 64 + c4);
            }
            int ex = __shfl((int)pea.x, jj, 64);
            int ey = __shfl((int)pea.y, jj, 64);
            int ez = __shfl((int)pea.z, jj, 64);
            int ew = __shfl((int)pea.w, jj, 64);
            float eav[8];
            unpack8_half(ex, ey, ez, ew, eav);
            const __half2* hp = (const __half2*)&cur;
            float2 lo = __half22float2(hp[0]);
            float2 hi = __half22float2(hp[1]);
            float4 xs = make_float4(lo.x, lo.y, hi.x, hi.y);
            float4 ee = make_float4(0.f, 0.f, 0.f, 0.f);
#pragma unroll
            for (int k = 0; k < 8; k++) {
                ee.x += eav[k] * we[k].x; ee.y += eav[k] * we[k].y;
                ee.z += eav[k] * we[k].z; ee.w += eav[k] * we[k].w;
            }
            float4 v;
            v.x = xs.x + xr4.x + ee.x; v.y = xs.y + xr4.y + ee.y;
            v.z = xs.z + xr4.z + ee.z; v.w = xs.w + xr4.w + ee.w;
            v.x = v.x > 0.f ? v.x : 0.2f * v.x;
            v.y = v.y > 0.f ? v.y : 0.2f * v.y;
            v.z = v.z > 0.f ? v.z : 0.2f * v.z;
            v.w = v.w > 0.f ? v.w : 0.2f * v.w;
            float p = v.x * at4.x + v.y * at4.y + v.z * at4.z + v.w * at4.w;
            p += __shfl_xor(p, 1, 64);
            p += __shfl_xor(p, 2, 64);
            p += __shfl_xor(p, 4, 64);
            p += __shfl_xor(p, 8, 64);        // 16-lane segment reduce
            bool valid = jj < cnt;
            float wgt = valid ? expf(p) : 0.f;
            acc.x += wgt * xs.x;
            acc.y += wgt * xs.y;
            acc.z += wgt * xs.z;
            acc.w += wgt * xs.w;
            sumw += wgt;
        }
        cb += cnt;
    }
#pragma unroll
    for (int d = 16; d <= 32; d <<= 1) {
        acc.x += __shfl_xor(acc.x, d, 64);
        acc.y += __shfl_xor(acc.y, d, 64);
        acc.z += __shfl_xor(acc.z, d, 64);
        acc.w += __shfl_xor(acc.w, d, 64);
        sumw  += __shfl_xor(sumw, d, 64);
    }
    float inv = 1.f / (sumw + 1e-16f);
    float4 bi = *(const float4*)(bias2 + c4);
    float4 g4 = *(const float4*)(g + c4);
    float4 b4 = *(const float4*)(bb_ + c4);
    float4 m4 = *(const float4*)(mm_ + c4);
    float4 v4 = *(const float4*)(vv_ + c4);
    float4 o;
    o.x = acc.x * inv + bi.x; o.y = acc.y * inv + bi.y;
    o.z = acc.z * inv + bi.z; o.w = acc.w * inv + bi.w;
    o.x = (o.x - m4.x) * rsqrtf(v4.x + 1e-5f) * g4.x + b4.x;
    o.y = (o.y - m4.y) * rsqrtf(v4.y + 1e-5f) * g4.y + b4.y;
    o.z = (o.z - m4.z) * rsqrtf(v4.z + 1e-5f) * g4.z + b4.z;
    o.w = (o.w - m4.w) * rsqrtf(v4.w + 1e-5f) * g4.w + b4.w;
    if (seg == 0) {
        o.x = elu_f(o.x); o.y = elu_f(o.y); o.z = elu_f(o.z); o.w = elu_f(o.w);
        *(uint2*)(h2h + (size_t)node * 64 + c4) = f4_to_half4(o);
    }
}

// ---------- u = h2@Wm1[0:64], v = h2@Wm1[64:128]  (fp16 out, no bias) ----------
__global__ __launch_bounds__(256) void k_uv(const __half* __restrict__ h2h, const float* __restrict__ Wm1,
                                            __half* __restrict__ uh, __half* __restrict__ vh, int N) {
    __shared__ float sh[32][32];    // [kk][node]
    __shared__ float sw[32][128];   // [kk][col]  (u cols 0..63, v cols 64..127)
    int t = threadIdx.x;
    int tr = t >> 5, tc = t & 31;
    int n0 = blockIdx.x * 32;
    float acc[4][4];
#pragma unroll
    for (int i = 0; i < 4; i++)
#pragma unroll
        for (int j = 0; j < 4; j++) acc[i][j] = 0.f;
    for (int k0 = 0; k0 < 64; k0 += 32) {
        {
            int n = t >> 3, kk0 = (t & 7) * 4;
            int gn = n0 + n;
            float4 hv = make_float4(0.f, 0.f, 0.f, 0.f);
            if (gn < N) hv = half4_to_f4(*(const uint2*)(h2h + (size_t)gn * 64 + k0 + kk0));
            sh[kk0 + 0][n] = hv.x; sh[kk0 + 1][n] = hv.y; sh[kk0 + 2][n] = hv.z; sh[kk0 + 3][n] = hv.w;
        }
        for (int i = t; i < 32 * 128; i += 256) {
            int kk = i >> 7, c = i & 127;
            sw[kk][c] = (c < 64) ? Wm1[(size_t)(k0 + kk) * 64 + c]
                                 : Wm1[(size_t)(64 + k0 + kk) * 64 + (c - 64)];
        }
        __syncthreads();
#pragma unroll
        for (int kk = 0; kk < 32; kk++) {
            float4 hv = *(const float4*)&sh[kk][tr * 4];
            float4 wv = *(const float4*)&sw[kk][tc * 4];
            float hh[4] = { hv.x, hv.y, hv.z, hv.w };
            float wwv[4] = { wv.x, wv.y, wv.z, wv.w };
#pragma unroll
            for (int i = 0; i < 4; i++)
#pragma unroll
                for (int j = 0; j < 4; j++) acc[i][j] += hh[i] * wwv[j];
        }
        __syncthreads();
    }
#pragma unroll
    for (int i = 0; i < 4; i++) {
        int gn = n0 + tr * 4 + i;
        if (gn >= N) continue;
#pragma unroll
        for (int j = 0; j < 4; j++) {
            int c = tc * 4 + j;
            if (c < 64) uh[(size_t)gn * 64 + c] = __float2half(acc[i][j]);
            else        vh[(size_t)gn * 64 + (c - 64)] = __float2half(acc[i][j]);
        }
    }
}

// ---------- edge MLP head v3: inline weA (fp16 ea); z1 = gelu(u[r]+v[c]+weA); layer2+3 fused ----------
__global__ __launch_bounds__(256) void k_mlp2(const __half* __restrict__ uh, const __half* __restrict__ vh,
                                              const __half* __restrict__ eah, const int* __restrict__ ei,
                                              const float* __restrict__ Wm1, const float* __restrict__ bm1,
                                              const float* __restrict__ Wm2, const float* __restrict__ bm2,
                                              const float* __restrict__ Wm3, const float* __restrict__ bm3,
                                              float* __restrict__ out, int E) {
    __shared__ float sw2[64 * 32];
    __shared__ float sW1e[8 * 64];
    __shared__ float sb1[64];
    __shared__ int sre[64], sce[64];
    __shared__ float z1[64 * 68];
    int t = threadIdx.x;
    for (int i = t; i < 64 * 32; i += 256) sw2[i] = Wm2[i];
    for (int i = t; i < 512; i += 256) sW1e[i] = Wm1[128 * 64 + i];
    if (t < 64) sb1[t] = bm1[t];
    int e0 = blockIdx.x * 64;
    if (t < 64) {
        int e = e0 + t;
        if (e < E) { sre[t] = ei[e]; sce[t] = ei[E + e]; }
        else { sre[t] = 0; sce[t] = 0; }
    }
    __syncthreads();
    for (int i = t; i < 512; i += 256) {
        int el = i >> 3, q = i & 7;
        int r = sre[el], c = sce[el];
        uint4 ru = *(const uint4*)(uh + (size_t)r * 64 + q * 8);
        uint4 rv = *(const uint4*)(vh + (size_t)c * 64 + q * 8);
        uint4 rea = *(const uint4*)(eah + (size_t)(e0 + el) * 8);
        float av[8];
        unpack8_half((int)rea.x, (int)rea.y, (int)rea.z, (int)rea.w, av);
        float wv[8];
#pragma unroll
        for (int j = 0; j < 8; j++) wv[j] = sb1[q * 8 + j];
#pragma unroll
        for (int k = 0; k < 8; k++) {
            float a = av[k];
#pragma unroll
            for (int j = 0; j < 8; j++) wv[j] += a * sW1e[k * 64 + q * 8 + j];
        }
        float4 uhi, vhi;
        float4 ulo = half8_lo_hi(ru, &uhi);
        float4 vlo = half8_lo_hi(rv, &vhi);
        float4 zlo, zhi;
        zlo.x = gelu_f(ulo.x + vlo.x + wv[0]);
        zlo.y = gelu_f(ulo.y + vlo.y + wv[1]);
        zlo.z = gelu_f(ulo.z + vlo.z + wv[2]);
        zlo.w = gelu_f(ulo.w + vlo.w + wv[3]);
        zhi.x = gelu_f(uhi.x + vhi.x + wv[4]);
        zhi.y = gelu_f(uhi.y + vhi.y + wv[5]);
        zhi.z = gelu_f(uhi.z + vhi.z + wv[6]);
        zhi.w = gelu_f(uhi.w + vhi.w + wv[7]);
        *(float4*)(z1 + el * 68 + q * 8)     = zlo;
        *(float4*)(z1 + el * 68 + q * 8 + 4) = zhi;
    }
    __syncthreads();
    int tr = t >> 3;
    int tc = t & 7;
    float b2[4], w3[4];
#pragma unroll
    for (int j = 0; j < 4; j++) { b2[j] = bm2[tc * 4 + j]; w3[j] = Wm3[tc * 4 + j]; }
    float b3 = bm3[0];
    float acc0[4], acc1[4];
#pragma unroll
    for (int j = 0; j < 4; j++) { acc0[j] = 0.f; acc1[j] = 0.f; }
    const float* z0p = z1 + (tr * 2 + 0) * 68;
    const float* z1p = z1 + (tr * 2 + 1) * 68;
#pragma unroll 8
    for (int k = 0; k < 64; k++) {
        float4 wv = *(const float4*)(sw2 + k * 32 + tc * 4);
        float a0 = z0p[k];
        float a1 = z1p[k];
        acc0[0] += a0 * wv.x; acc0[1] += a0 * wv.y; acc0[2] += a0 * wv.z; acc0[3] += a0 * wv.w;
        acc1[0] += a1 * wv.x; acc1[1] += a1 * wv.y; acc1[2] += a1 * wv.z; acc1[3] += a1 * wv.w;
    }
    float p0 = 0.f, p1 = 0.f;
#pragma unroll
    for (int j = 0; j < 4; j++) {
        p0 += gelu_f(acc0[j] + b2[j]) * w3[j];
        p1 += gelu_f(acc1[j] + b2[j]) * w3[j];
    }
    p0 += __shfl_xor(p0, 1, 64); p0 += __shfl_xor(p0, 2, 64); p0 += __shfl_xor(p0, 4, 64);
    p1 += __shfl_xor(p1, 1, 64); p1 += __shfl_xor(p1, 2, 64); p1 += __shfl_xor(p1, 4, 64);
    if (tc == 0) {
        int e = e0 + tr * 2;
        if (e < E)     out[e]     = 1.f / (1.f + expf(-(p0 + b3)));
        if (e + 1 < E) out[e + 1] = 1.f / (1.f + expf(-(p1 + b3)));
    }
}

extern "C" void kernel_launch(void* const* d_in, const int* in_sizes, int n_in,
                              void* d_out, int out_size, void* d_ws, size_t ws_size,
                              hipStream_t stream) {
    const float* x    = (const float*)d_in[0];
    const int*   ei   = (const int*)d_in[1];
    const float* ea   = (const float*)d_in[2];
    const float* Wl1  = (const float*)d_in[3];
    const float* bl1  = (const float*)d_in[4];
    const float* Wr1  = (const float*)d_in[5];
    const float* br1  = (const float*)d_in[6];
    const float* We1  = (const float*)d_in[7];
    const float* att1 = (const float*)d_in[8];
    const float* bias1= (const float*)d_in[9];
    const float* Wl2  = (const float*)d_in[10];
    const float* bl2  = (const float*)d_in[11];
    const float* Wr2  = (const float*)d_in[12];
    const float* br2  = (const float*)d_in[13];
    const float* We2  = (const float*)d_in[14];
    const float* att2 = (const float*)d_in[15];
    const float* bias2= (const float*)d_in[16];
    const float* bn1g = (const float*)d_in[17];
    const float* bn1b = (const float*)d_in[18];
    const float* bn1m = (const float*)d_in[19];
    const float* bn1v = (const float*)d_in[20];
    const float* bn2g = (const float*)d_in[21];
    const float* bn2b = (const float*)d_in[22];
    const float* bn2m = (const float*)d_in[23];
    const float* bn2v = (const float*)d_in[24];
    const float* Wres = (const float*)d_in[25];
    const float* Wm1  = (const float*)d_in[26];
    const float* bm1  = (const float*)d_in[27];
    const float* Wm2  = (const float*)d_in[28];
    const float* bm2  = (const float*)d_in[29];
    const float* Wm3  = (const float*)d_in[30];
    const float* bm3  = (const float*)d_in[31];
    float* out = (float*)d_out;
    float* ws = (float*)d_ws;

    const int N = NN, E = EE, Etot = ETOT;

    // workspace layout (floats)
    float* ea_sum   = ws;                                     // 16
    int*   counts   = (int*)(ws + 16);                        // N
    int*   off      = (int*)(ws + 16 + (size_t)N);            // N+16
    int*   cursor   = (int*)(ws + 32 + (size_t)2 * N);        // N
    int*   csr_src  = (int*)(ws + 32 + (size_t)3 * N);        // Etot
    int*   csr_eid  = (int*)(ws + 32 + (size_t)3 * N + Etot); // Etot
    size_t base     = 32 + (size_t)3 * N + (size_t)2 * Etot;
    __half* xl1h    = (__half*)(ws + base);                   // 256N halfs = 128N floats
    __half* xl2h    = xl1h;                                   // reuses (xl1h dead after k_fagg1)
    __half* h2h     = (__half*)(ws + base + (size_t)128 * N); // 64N halfs = 32N floats
    __half* xr1h    = (__half*)(ws + base + (size_t)160 * N); // 256N halfs = 128N floats
    __half* h1h     = xr1h;                                   // in-place (own row read before write)
    __half* xr2h    = (__half*)(ws + base + (size_t)288 * N); // 64N halfs = 32N floats
    __half* uh      = xr2h;                                   // overlays xr2h (dead after k_fagg2)
    __half* vh      = uh + (size_t)64 * N;                    // next 32N floats
    __half* eah     = (__half*)(ws + base + (size_t)352 * N); // 8E halfs = 4E floats

    hipMemsetAsync(ea_sum, 0, 16 * sizeof(float), stream);
    hipMemsetAsync(counts, 0, (size_t)N * sizeof(int), stream);

    int S = (Etot + 255) / 256;
    k_init<<<256 + S, 256, 0, stream>>>(ea, ea_sum, eah, ei, counts, E, N);
    k_scan<<<1, 1024, 0, stream>>>(counts, off, cursor, N);
    k_scat_nt1<<<S + (N + 31) / 32, 256, 0, stream>>>(ei, cursor, csr_src, csr_eid,
                                                      x, Wl1, bl1, Wr1, br1, xl1h, xr1h, E, N);
    k_fagg1<<<(N + 3) / 4, 256, 0, stream>>>(xl1h, xr1h, off, csr_src, csr_eid, eah, ea_sum,
                                             We1, att1, bias1, x, Wres,
                                             bn1g, bn1b, bn1m, bn1v, h1h, E, N);
    k_xlr2<<<(N + 31) / 32, 256, 0, stream>>>(h1h, Wl2, bl2, Wr2, br2, xl2h, xr2h, N);
    k_fagg2<<<(N + 3) / 4, 256, 0, stream>>>(xl2h, xr2h, off, csr_src, csr_eid, eah, ea_sum,
                                             We2, att2, bias2,
                                             bn2g, bn2b, bn2m, bn2v, h2h, E, N);
    k_uv<<<(N + 31) / 32, 256, 0, stream>>>(h2h, Wm1, uh, vh, N);
    k_mlp2<<<(E + 63) / 64, 256, 0, stream>>>(uh, vh, eah, ei, Wm1, bm1, Wm2, bm2, Wm3, bm3, out, E);
}